// Round 2
// baseline (401.318 us; speedup 1.0000x reference)
//
#include <hip/hip_runtime.h>
#include <hip/hip_bf16.h>
#include <math.h>

typedef __bf16 bf16_t;
typedef bf16_t bf16x8 __attribute__((ext_vector_type(8)));
typedef float  f32x4  __attribute__((ext_vector_type(4)));

#define SEQ 200
#define DD  64
#define RS2 72   // per-wave h-tile LDS row stride (144 B, 16B-aligned b128 reads)

#define MFMA(a, b, c) __builtin_amdgcn_mfma_f32_16x16x32_bf16((a), (b), (c), 0, 0, 0)
#define LGKM0() asm volatile("s_waitcnt lgkmcnt(0)" ::: "memory")

// ---------------- prep kernel (1 block): weight transforms only ----------------
__global__ __launch_bounds__(256) void prep_kernel(
    const float* __restrict__ W1, const float* __restrict__ W2,
    bf16_t* __restrict__ Wbc, bf16_t* __restrict__ W1dt,
    bf16_t* __restrict__ W2t, float* __restrict__ W1sT)
{
  const int tid = threadIdx.x;
  for (int i = tid; i < 64 * 64; i += 256) {
    int n = i >> 6, k = i & 63;
    Wbc[i]  = (bf16_t)(W1[(64 + k) * 64 + n] - W1[(128 + k) * 64 + n]);
    W1dt[i] = (bf16_t)(W1[(192 + k) * 64 + n]);
    // W1sT[n][d] = W1[d][n] + W1[128+d][n]  (fp32, for exact Q)
    W1sT[i] = W1[k * 64 + n] + W1[(128 + k) * 64 + n];
  }
  for (int i = tid; i < 32 * 64; i += 256) {
    int n = i >> 6, k = i & 63;
    W2t[i] = (bf16_t)(W2[k * 32 + n]);
  }
}

// ---------------- main kernel: ONE WAVE per batch row, no __syncthreads ----------------
__global__ __launch_bounds__(256, 3) void din_kernel(
    const float* __restrict__ em, const float* __restrict__ eu,
    const float* __restrict__ Xu, const float* __restrict__ b1,
    const float* __restrict__ b2, const float* __restrict__ W3,
    const float* __restrict__ b3, const float* __restrict__ gam,
    const float* __restrict__ bet, const float* __restrict__ mmean,
    const float* __restrict__ mvar, const bf16_t* __restrict__ Wbc,
    const bf16_t* __restrict__ W1dt, const bf16_t* __restrict__ W2t,
    const float* __restrict__ W1sT, float* __restrict__ out, int Btot)
{
  __shared__ __align__(16) bf16_t hbuf[4][16 * RS2];  // per-wave h-tile transpose buf
  __shared__ __align__(16) float  lbuf[4][16];        // per-wave logits tile
  __shared__ __align__(16) float  ebuf[4][64];        // per-wave em broadcast

  const int tid  = threadIdx.x;
  const int lane = tid & 63;
  const int wid  = tid >> 6;
  const int g    = lane >> 4;
  const int l16  = lane & 15;
  const int b    = blockIdx.x * 4 + wid;
  if (b >= Btot) return;   // wave-uniform, no barriers in this kernel

  bf16_t* hw = hbuf[wid];
  float*  lw = lbuf[wid];
  float*  ew = ebuf[wid];

  // ---- em row + slices ----
  const float* emr = em + (size_t)b * DD;
  const float em_l = emr[lane];
  float4 ef[4];
  ef[0] = *(const float4*)&emr[8 * g];
  ef[1] = *(const float4*)&emr[8 * g + 4];
  ef[2] = *(const float4*)&emr[32 + 8 * g];
  ef[3] = *(const float4*)&emr[32 + 8 * g + 4];

  // ---- B-fragments: stage-1 folded weights (Wbc + em_k * W1dt), all 4 n-tiles ----
  const bf16x8* Wbc8  = (const bf16x8*)Wbc;
  const bf16x8* W1dt8 = (const bf16x8*)W1dt;
  const bf16x8* W2t8  = (const bf16x8*)W2t;
  bf16x8 bB[4][2];
  #pragma unroll
  for (int j = 0; j < 4; ++j)
    #pragma unroll
    for (int c = 0; c < 2; ++c) {
      bf16x8 wbc = Wbc8[(16 * j + l16) * 8 + 4 * c + g];
      bf16x8 w1d = W1dt8[(16 * j + l16) * 8 + 4 * c + g];
      float4 e0 = ef[2 * c], e1 = ef[2 * c + 1];
      bf16x8 r;
      r[0] = (bf16_t)((float)wbc[0] + e0.x * (float)w1d[0]);
      r[1] = (bf16_t)((float)wbc[1] + e0.y * (float)w1d[1]);
      r[2] = (bf16_t)((float)wbc[2] + e0.z * (float)w1d[2]);
      r[3] = (bf16_t)((float)wbc[3] + e0.w * (float)w1d[3]);
      r[4] = (bf16_t)((float)wbc[4] + e1.x * (float)w1d[4]);
      r[5] = (bf16_t)((float)wbc[5] + e1.y * (float)w1d[5]);
      r[6] = (bf16_t)((float)wbc[6] + e1.z * (float)w1d[6]);
      r[7] = (bf16_t)((float)wbc[7] + e1.w * (float)w1d[7]);
      bB[j][c] = r;
    }

  bf16x8 W2f[2][2];
  #pragma unroll
  for (int c = 0; c < 2; ++c)
    #pragma unroll
    for (int u = 0; u < 2; ++u)
      W2f[c][u] = W2t8[(16 * u + l16) * 8 + 4 * c + g];

  const float b2v0 = b2[l16], b2v1 = b2[16 + l16];
  const float w3v0 = W3[l16], w3v1 = W3[16 + l16];
  const float b3s  = b3[0];

  // ---- Q per row (exact fp32): q[lane] = b1[lane] + sum_d em[d]*W1sT[lane][d] ----
  ew[lane] = em_l;
  LGKM0();
  float q = b1[lane];
  const float4* wq = (const float4*)(W1sT + lane * 64);
  #pragma unroll
  for (int dd = 0; dd < 16; ++dd) {
    float4 wv = wq[dd];
    float4 ev = *(const float4*)&ew[4 * dd];   // uniform-address broadcast read
    q += ev.x * wv.x + ev.y * wv.y + ev.z * wv.z + ev.w * wv.w;
  }
  float qn[4];
  #pragma unroll
  for (int j = 0; j < 4; ++j) qn[j] = __shfl(q, 16 * j + l16);

  // ---- online-softmax state ----
  float m = -INFINITY, Z = 0.f;
  float P[16];
  #pragma unroll
  for (int e = 0; e < 16; ++e) P[e] = 0.f;

  const float4* Xr = (const float4*)(Xu + (size_t)b * SEQ * DD);

  auto LOADT = [&](int t, float4* X) {
    if (t == 12 && l16 >= 8) {
      X[0] = X[1] = X[2] = X[3] = make_float4(0.f, 0.f, 0.f, 0.f);
    } else {
      const float4* p = Xr + ((16 * t + l16) * 16 + 2 * g);
      X[0] = p[0]; X[1] = p[1]; X[2] = p[8]; X[3] = p[9];
    }
  };

  auto PROC = [&](int t, const float4* X) {
    // convert to MFMA A-fragments (row = 16t+l16, k = 8g+e / 32+8g+e)
    bf16x8 a0, a1;
    a0[0] = (bf16_t)X[0].x; a0[1] = (bf16_t)X[0].y; a0[2] = (bf16_t)X[0].z; a0[3] = (bf16_t)X[0].w;
    a0[4] = (bf16_t)X[1].x; a0[5] = (bf16_t)X[1].y; a0[6] = (bf16_t)X[1].z; a0[7] = (bf16_t)X[1].w;
    a1[0] = (bf16_t)X[2].x; a1[1] = (bf16_t)X[2].y; a1[2] = (bf16_t)X[2].z; a1[3] = (bf16_t)X[2].w;
    a1[4] = (bf16_t)X[3].x; a1[5] = (bf16_t)X[3].y; a1[6] = (bf16_t)X[3].z; a1[7] = (bf16_t)X[3].w;

    // stage 1: 4 n-tiles of 16 cols, K=64
    f32x4 c[4];
    #pragma unroll
    for (int j = 0; j < 4; ++j) {
      f32x4 z = {0.f, 0.f, 0.f, 0.f};
      z = MFMA(a0, bB[j][0], z);
      z = MFMA(a1, bB[j][1], z);
      c[j] = z;
    }
    // relu(+q) -> transpose via per-wave LDS (C layout: col=l16, row=4g+r)
    #pragma unroll
    for (int j = 0; j < 4; ++j)
      #pragma unroll
      for (int r = 0; r < 4; ++r) {
        float v = c[j][r] + qn[j];
        hw[(4 * g + r) * RS2 + 16 * j + l16] = (bf16_t)fmaxf(v, 0.f);
      }
    LGKM0();
    bf16x8 h0 = *(const bf16x8*)&hw[l16 * RS2 + 8 * g];
    bf16x8 h1 = *(const bf16x8*)&hw[l16 * RS2 + 32 + 8 * g];

    // stage 2: [16x64]@[64x32]
    f32x4 d0 = {0.f, 0.f, 0.f, 0.f}, d1 = {0.f, 0.f, 0.f, 0.f};
    d0 = MFMA(h0, W2f[0][0], d0);
    d0 = MFMA(h1, W2f[1][0], d0);
    d1 = MFMA(h0, W2f[0][1], d1);
    d1 = MFMA(h1, W2f[1][1], d1);

    // stage 3: relu + dot(W3) -> per-row logits
    float pr[4];
    #pragma unroll
    for (int r = 0; r < 4; ++r)
      pr[r] = fmaxf(d0[r] + b2v0, 0.f) * w3v0 + fmaxf(d1[r] + b2v1, 0.f) * w3v1;
    #pragma unroll
    for (int o = 1; o < 16; o <<= 1)
      #pragma unroll
      for (int r = 0; r < 4; ++r) pr[r] += __shfl_xor(pr[r], o);
    if (l16 == 0) {
      #pragma unroll
      for (int r = 0; r < 4; ++r) {
        int s = 16 * t + 4 * g + r;
        lw[4 * g + r] = (s < SEQ) ? (pr[r] + b3s) : -INFINITY;
      }
    }
    LGKM0();
    float lv = lw[l16];            // logit of THIS lane's Xu row (s = 16t+l16)

    // online softmax update (wave-uniform m, Z; per-lane e-weight)
    float tm = lv;
    #pragma unroll
    for (int o = 1; o < 16; o <<= 1) tm = fmaxf(tm, __shfl_xor(tm, o));
    float mn = fmaxf(m, tm);
    float al = __expf(m - mn);     // first tile: exp(-inf)=0, states are 0 anyway
    float ee = __expf(lv - mn);    // invalid rows: exp(-inf)=0
    float S = ee;
    #pragma unroll
    for (int o = 1; o < 16; o <<= 1) S += __shfl_xor(S, o);
    Z = Z * al + S;
    #pragma unroll
    for (int e = 0; e < 8; ++e) {
      P[e]     = P[e]     * al + ee * (float)a0[e];
      P[8 + e] = P[8 + e] * al + ee * (float)a1[e];
    }
    m = mn;
  };

  // ---- 13-tile pipeline, double-buffered global loads ----
  float4 X0[4], X1[4];
  LOADT(0, X0);
  #pragma unroll
  for (int t = 0; t < 13; ++t) {
    float4* cur = (t & 1) ? X1 : X0;
    float4* nxt = (t & 1) ? X0 : X1;
    if (t < 12) LOADT(t + 1, nxt);
    PROC(t, cur);
  }

  // ---- finalize pooling: reduce P over the 16 row-classes, scale by 1/Z ----
  const float invZ = 1.f / Z;
  #pragma unroll
  for (int o = 1; o < 16; o <<= 1)
    #pragma unroll
    for (int e = 0; e < 16; ++e) P[e] += __shfl_xor(P[e], o);
  float* pw = (float*)hw;          // reuse h-tile buffer
  if (l16 == 0) {
    #pragma unroll
    for (int e = 0; e < 8; ++e) {
      pw[8 * g + e]      = P[e]     * invZ;
      pw[32 + 8 * g + e] = P[8 + e] * invZ;
    }
  }
  LGKM0();
  float pooled = pw[lane];

  // ---- BN + concat output ----
  float o0 = (pooled - mmean[lane]) * rsqrtf(mvar[lane] + 1e-3f) * gam[lane] + bet[lane];
  float o1 = (em_l - mmean[64 + lane]) * rsqrtf(mvar[64 + lane] + 1e-3f) * gam[64 + lane] + bet[64 + lane];
  float o2 = eu[(size_t)b * 64 + lane];
  float* ob = out + (size_t)b * 192;
  ob[lane]       = o0;
  ob[64 + lane]  = o1;
  ob[128 + lane] = o2;
}

extern "C" void kernel_launch(void* const* d_in, const int* in_sizes, int n_in,
                              void* d_out, int out_size, void* d_ws, size_t ws_size,
                              hipStream_t stream) {
  const float* em = (const float*)d_in[0];
  const float* eu = (const float*)d_in[1];
  const float* Xu = (const float*)d_in[2];
  const float* W1 = (const float*)d_in[3];
  const float* b1 = (const float*)d_in[4];
  const float* W2 = (const float*)d_in[5];
  const float* b2 = (const float*)d_in[6];
  const float* W3 = (const float*)d_in[7];
  const float* b3 = (const float*)d_in[8];
  const float* ga = (const float*)d_in[9];
  const float* be = (const float*)d_in[10];
  const float* mm = (const float*)d_in[11];
  const float* mv = (const float*)d_in[12];
  int B = in_sizes[0] / DD;

  float*  W1sT = (float*)d_ws;                          // 16 KB fp32
  bf16_t* Wbc  = (bf16_t*)((char*)d_ws + 64 * 64 * 4);  // 8 KB
  bf16_t* W1dt = Wbc + 64 * 64;                         // 8 KB
  bf16_t* W2t  = W1dt + 64 * 64;                        // 4 KB

  prep_kernel<<<1, 256, 0, stream>>>(W1, W2, Wbc, W1dt, W2t, W1sT);
  din_kernel<<<(B + 3) / 4, 256, 0, stream>>>(em, eu, Xu, b1, b2, W3, b3, ga, be,
                                              mm, mv, Wbc, W1dt, W2t, W1sT,
                                              (float*)d_out, B);
}